// Round 1
// baseline (265.215 us; speedup 1.0000x reference)
//
#include <hip/hip_runtime.h>
#include <stdint.h>

#define B_ 4
#define S_ 1001
#define SP 1008    // padded rows (63 * 16)
#define SPAD 1024  // padded t dimension (32 * 32)
#define EIN_ 256
#define EOUT_ 64
#define H_ 10
#define NCOL 640   // H*EOUT
#define NCOL3 1920
#define SCW 1016   // sc row stride in bf16 (1008 cols + 8 pad); 16*SCW*2+16+64 = 32592 B -> 5 blocks/CU

typedef short bf16x8 __attribute__((ext_vector_type(8)));
typedef short bf16x4 __attribute__((ext_vector_type(4)));
typedef float f32x4 __attribute__((ext_vector_type(4)));

__device__ __forceinline__ unsigned short f2bf(float f) {
  unsigned u = __float_as_uint(f);
  u += 0x7FFFu + ((u >> 16) & 1u);  // RTNE (inputs finite)
  return (unsigned short)(u >> 16);
}
__device__ __forceinline__ float bf2f(unsigned short h) {
  return __uint_as_float(((unsigned)h) << 16);
}

// ---- kernel 1: fp32 -> bf16 (x padded, W concat) + mask zero-padded fp32 ----
__global__ __launch_bounds__(256) void convert_kernel(
    const float* __restrict__ x, const float* __restrict__ Wq,
    const float* __restrict__ Wk, const float* __restrict__ Wv,
    const float* __restrict__ mask, unsigned short* __restrict__ xbf,
    unsigned short* __restrict__ wbf, float* __restrict__ mpad) {
  int i = blockIdx.x * 256 + threadIdx.x;
  const int N1 = B_ * SP * EIN_;   // 1,032,192
  const int N2 = NCOL3 * EIN_;     // 491,520
  const int N3 = SP * SPAD;        // 1,032,192
  if (i < N1) {
    int b = i / (SP * EIN_);
    int rem = i % (SP * EIN_);
    int row = rem / EIN_;
    int e = rem % EIN_;
    float v = (row < S_) ? x[((size_t)(b * S_ + row)) * EIN_ + e] : 0.0f;
    xbf[i] = f2bf(v);
  } else if (i < N1 + N2) {
    int j = i - N1;
    int col = j / EIN_;
    int e = j % EIN_;
    int mat = col / NCOL;
    int hcol = col % NCOL;
    const float* W = (mat == 0) ? Wq : (mat == 1) ? Wk : Wv;
    wbf[j] = f2bf(W[(size_t)hcol * EIN_ + e]);
  } else if (i < N1 + N2 + N3) {
    int j = i - N1 - N2;
    int row = j >> 10;
    int col = j & 1023;
    mpad[j] = (row < S_ && col < S_) ? mask[(size_t)row * S_ + col] : 0.0f;
  }
}

// ---------------- kernel 2: projection GEMM (MFMA bf16), 6-way N split ------
__global__ __launch_bounds__(256) void proj_kernel(
    const unsigned short* __restrict__ xbf, const unsigned short* __restrict__ wbf,
    const float* __restrict__ bq, const float* __restrict__ bk,
    const float* __restrict__ bv, unsigned short* __restrict__ qbf,
    unsigned short* __restrict__ kbf, unsigned short* __restrict__ vrow) {
  int tid = threadIdx.x;
  int wv_ = tid >> 6;
  int l = tid & 63;
  int qd = l >> 4;
  int c = l & 15;
  int bid = blockIdx.x;
  int g = bid % 6;
  int t2 = bid / 6;
  int b = t2 / 63;
  int tile = t2 % 63;
  int s0 = tile * 16;

  bf16x8 af[8];
  const unsigned short* xrowp = xbf + (size_t)(b * SP + s0 + c) * EIN_;
#pragma unroll
  for (int ks = 0; ks < 8; ++ks)
    af[ks] = *(const bf16x8*)(xrowp + ks * 32 + qd * 8);

  for (int nt = g * 20 + wv_; nt < g * 20 + 20; nt += 4) {
    int col0 = nt * 16;
    f32x4 acc = {0.f, 0.f, 0.f, 0.f};
    const unsigned short* wrow = wbf + (size_t)(col0 + c) * EIN_;
#pragma unroll
    for (int ks = 0; ks < 8; ++ks) {
      bf16x8 bfg = *(const bf16x8*)(wrow + ks * 32 + qd * 8);
      acc = __builtin_amdgcn_mfma_f32_16x16x32_bf16(af[ks], bfg, acc, 0, 0, 0);
    }
    int col = col0 + c;
    int mat = col / NCOL;
    int hcol = col % NCOL;
    int hh = hcol >> 6;
    int o = hcol & 63;
    const float* bias = (mat == 0) ? bq : (mat == 1) ? bk : bv;
    float bb = bias[hcol];
    unsigned short* dst = (mat == 0) ? qbf : (mat == 1) ? kbf : vrow;
    size_t base = ((size_t)(b * H_ + hh)) * SPAD * EOUT_ + o;
#pragma unroll
    for (int i = 0; i < 4; ++i) {
      int srow = s0 + qd * 4 + i;
      float v = (srow < S_) ? (acc[i] + bb) : 0.0f;  // zero pad rows
      dst[base + (size_t)srow * EOUT_] = f2bf(v);
    }
  }
}

// ---------------- kernel 3: v [t][o] -> vT [o][t] ----------------
// Explicitly zeroes vT for t >= 1008 (proj never writes those rows), so the
// attention kernel's k-tail MFMAs see guaranteed-zero B fragments.
__global__ __launch_bounds__(256) void transpose_v(
    const unsigned short* __restrict__ vrow, unsigned short* __restrict__ vT) {
  __shared__ unsigned short tl[64 * 65];
  int bid = blockIdx.x;
  int bh = bid >> 4;
  int t0 = (bid & 15) * 64;
  int tid = threadIdx.x;
#pragma unroll
  for (int i = 0; i < 16; ++i) {
    int idx = i * 256 + tid;
    int o = idx & 63;
    int t_l = idx >> 6;
    int row = t0 + t_l;
    tl[o * 65 + t_l] =
        (row < SP) ? vrow[((size_t)bh * SPAD + row) * EOUT_ + o] : (unsigned short)0;
  }
  __syncthreads();
#pragma unroll
  for (int i = 0; i < 16; ++i) {
    int idx = i * 256 + tid;
    int t_l = idx & 63;
    int o = idx >> 6;
    vT[((size_t)bh * EOUT_ + o) * SPAD + t0 + t_l] = tl[o * 65 + t_l];
  }
}

// ---------------- kernel 4: attention (concat out + rs export) ----------------
// LDS = 16*1016*2 + 16 (guard) + 64 (rs) = 32592 B -> 5 blocks/CU (was 33792 -> 3-4).
// XCD swizzle: same-tile blocks (which share the 64 KB mask slab) co-locate per XCD.
__global__ __launch_bounds__(256, 5) void attn_kernel(
    const unsigned short* __restrict__ qbf, const unsigned short* __restrict__ kbf,
    const unsigned short* __restrict__ vT, const float* __restrict__ mpad,
    float* __restrict__ rsbuf, float* __restrict__ out) {
  __shared__ unsigned short sc[16 * SCW + 8];  // +8 bf16 = 16 B zero guard
  __shared__ float rs[16];

  int tid = threadIdx.x;
  int wv_ = tid >> 6;
  int l = tid & 63;
  int qd = l >> 4;
  int c = l & 15;
  int bid0 = blockIdx.x;
  // XCD-aware swizzle: 2520 = 8 * 315. XCD x owns a contiguous range of the
  // (tile-major) linear id -> ~8 tiles x all 40 (b,h) per XCD -> mask L2-hot.
  int bid = (bid0 & 7) * 315 + (bid0 >> 3);
  int b = bid / (H_ * 63);
  int rem = bid % (H_ * 63);
  int h = rem / 63;
  int tile = rem % 63;
  int s0 = tile * 16;

  if (tid < 16) rs[tid] = 0.0f;

  float* concat = out;  // [B,S,640]

  size_t bh = (size_t)(b * H_ + h);
  const unsigned short* qb = qbf + bh * SPAD * EOUT_;
  const unsigned short* kb = kbf + bh * SPAD * EOUT_;
  const unsigned short* vb = vT + bh * EOUT_ * SPAD;

  // ---- phase A: scores = (Q K^T)/16, bf16 into LDS ----
  bf16x8 aq0 = *(const bf16x8*)(qb + (size_t)(s0 + c) * EOUT_ + qd * 8);
  bf16x8 aq1 = *(const bf16x8*)(qb + (size_t)(s0 + c) * EOUT_ + 32 + qd * 8);
  for (int tt = wv_; tt < 63; tt += 4) {
    int t0 = tt * 16;
    f32x4 acc = {0.f, 0.f, 0.f, 0.f};
    const unsigned short* krow = kb + (size_t)(t0 + c) * EOUT_ + qd * 8;
    acc = __builtin_amdgcn_mfma_f32_16x16x32_bf16(aq0, *(const bf16x8*)krow, acc, 0, 0, 0);
    acc = __builtin_amdgcn_mfma_f32_16x16x32_bf16(aq1, *(const bf16x8*)(krow + 32), acc, 0, 0, 0);
#pragma unroll
    for (int i = 0; i < 4; ++i)
      sc[(qd * 4 + i) * SCW + t0 + c] = f2bf(acc[i] * 0.0625f);
  }
  // cols 1008..1015 of each row + the 16 B guard after row 15 must be finite
  // (phase D k-tail reads them against zero B fragments): zero them.
  if (tid < 128) sc[(tid >> 3) * SCW + 1008 + (tid & 7)] = 0;
  if (tid < 8) sc[16 * SCW + tid] = 0;
  __syncthreads();

  // ---- phase B: row-per-wave, coalesced mask; l = exp(s)*mask, rs per row ----
#pragma unroll
  for (int rr = 0; rr < 4; ++rr) {
    int r = wv_ * 4 + rr;
    int srow = s0 + r;
    if (srow < S_) {
      const float* mrow = mpad + (size_t)srow * SPAD;
      float nacc = 0.0f;
#pragma unroll
      for (int ci = 0; ci < 3; ++ci) {
        int t0c = ci * 256 + 4 * l;
        bf16x4 sv = *(const bf16x4*)&sc[r * SCW + t0c];
        f32x4 mv = *(const f32x4*)(mrow + t0c);
        bf16x4 lvv;
#pragma unroll
        for (int j = 0; j < 4; ++j) {
          float e = __expf(bf2f((unsigned short)sv[j]));
          float lval = e * mv[j];  // mpad pad cols are 0 -> lval 0
          nacc += lval * lval;
          lvv[j] = (short)f2bf(lval);
        }
        *(bf16x4*)&sc[r * SCW + t0c] = lvv;
      }
      if (l < 60) {  // tail chunk: cols 768..1007
        int t0c = 768 + 4 * l;
        bf16x4 sv = *(const bf16x4*)&sc[r * SCW + t0c];
        f32x4 mv = *(const f32x4*)(mrow + t0c);
        bf16x4 lvv;
#pragma unroll
        for (int j = 0; j < 4; ++j) {
          float e = __expf(bf2f((unsigned short)sv[j]));
          float lval = e * mv[j];
          nacc += lval * lval;
          lvv[j] = (short)f2bf(lval);
        }
        *(bf16x4*)&sc[r * SCW + t0c] = lvv;
      }
      nacc += __shfl_xor(nacc, 1);
      nacc += __shfl_xor(nacc, 2);
      nacc += __shfl_xor(nacc, 4);
      nacc += __shfl_xor(nacc, 8);
      nacc += __shfl_xor(nacc, 16);
      nacc += __shfl_xor(nacc, 32);
      if (l == 0) rs[r] = 1.0f / fmaxf(sqrtf(nacc), 1e-12f);
    }
  }
  __syncthreads();

  if (tid < 16) rsbuf[((size_t)bh * 63 + tile) * 16 + tid] = rs[tid];

  // ---- phase D: out = (l V) * rs[row]; wave wv_ owns o in [16wv,16wv+16) ----
  // kstep 31 reads A cols 992..1023: 992..1007 real, 1008..1015 zeroed,
  // 1016..1023 wrap to next row / guard (finite) -- all multiplied by
  // vT[t>=1008] == 0, so contribution is exactly 0.
  f32x4 oacc = {0.f, 0.f, 0.f, 0.f};
  const unsigned short* vrow_ = vb + (size_t)(wv_ * 16 + c) * SPAD;
#pragma unroll
  for (int kstep = 0; kstep < 32; ++kstep) {
    bf16x8 afr = *(const bf16x8*)&sc[c * SCW + kstep * 32 + qd * 8];
    bf16x8 bfr = *(const bf16x8*)(vrow_ + kstep * 32 + qd * 8);
    oacc = __builtin_amdgcn_mfma_f32_16x16x32_bf16(afr, bfr, oacc, 0, 0, 0);
  }
#pragma unroll
  for (int i = 0; i < 4; ++i) {
    int row = qd * 4 + i;
    int srow = s0 + row;
    if (srow < S_)
      concat[((size_t)(b * S_) + srow) * NCOL + h * EOUT_ + wv_ * 16 + c] =
          oacc[i] * rs[row];
  }
}

// ---- kernel 5: wsum[b,s,t] = mask[s,t] * sum_h rs_h[s] * exp(score_h[s,t]) ----
// Recomputes QK^T per head (MFMA-cheap); exp + head-sum stay in C-layout regs.
__global__ __launch_bounds__(256) void wsum_kernel(
    const unsigned short* __restrict__ qbf, const unsigned short* __restrict__ kbf,
    const float* __restrict__ rsbuf, const float* __restrict__ mask,
    float* __restrict__ out) {
  __shared__ float wrs[H_ * 16];
  int tid = threadIdx.x;
  int wv_ = tid >> 6;
  int l = tid & 63;
  int qd = l >> 4;
  int c = l & 15;
  int bid0 = blockIdx.x;
  // XCD swizzle: 1008 = 8 * 126; co-locate same-tile blocks per XCD.
  int bid = (bid0 & 7) * 126 + (bid0 >> 3);
  int tchunk = bid & 3;
  int rem = bid >> 2;
  int tile = rem % 63;
  int b = rem / 63;
  int s0 = tile * 16;
  int tb = tchunk * 256 + wv_ * 64;

  if (tid < H_ * 16) {
    int h = tid >> 4, row = tid & 15;
    wrs[tid] = rsbuf[((size_t)(b * H_ + h) * 63 + tile) * 16 + row];
  }
  __syncthreads();

  float wacc[16];
#pragma unroll
  for (int i = 0; i < 16; ++i) wacc[i] = 0.0f;

  for (int h = 0; h < H_; ++h) {
    size_t bh = (size_t)(b * H_ + h);
    const unsigned short* qb = qbf + bh * SPAD * EOUT_;
    const unsigned short* kb = kbf + bh * SPAD * EOUT_;
    bf16x8 aq0 = *(const bf16x8*)(qb + (size_t)(s0 + c) * EOUT_ + qd * 8);
    bf16x8 aq1 = *(const bf16x8*)(qb + (size_t)(s0 + c) * EOUT_ + 32 + qd * 8);
    f32x4 acc[4];
#pragma unroll
    for (int st = 0; st < 4; ++st) {
      const unsigned short* krow =
          kb + (size_t)(tb + st * 16 + c) * EOUT_ + qd * 8;
      f32x4 a = {0.f, 0.f, 0.f, 0.f};
      a = __builtin_amdgcn_mfma_f32_16x16x32_bf16(aq0, *(const bf16x8*)krow, a, 0, 0, 0);
      a = __builtin_amdgcn_mfma_f32_16x16x32_bf16(aq1, *(const bf16x8*)(krow + 32), a, 0, 0, 0);
      acc[st] = a;
    }
#pragma unroll
    for (int st = 0; st < 4; ++st)
#pragma unroll
      for (int i = 0; i < 4; ++i)
        wacc[st * 4 + i] += wrs[h * 16 + qd * 4 + i] * __expf(acc[st][i] * 0.0625f);
  }

  float* wsum = out + (size_t)B_ * S_ * NCOL;
#pragma unroll
  for (int st = 0; st < 4; ++st) {
    int t = tb + st * 16 + c;
#pragma unroll
    for (int i = 0; i < 4; ++i) {
      int srow = s0 + qd * 4 + i;
      if (srow < S_ && t < S_)
        wsum[((size_t)b * S_ + srow) * S_ + t] =
            wacc[st * 4 + i] * mask[(size_t)srow * S_ + t];
    }
  }
}

extern "C" void kernel_launch(void* const* d_in, const int* in_sizes, int n_in,
                              void* d_out, int out_size, void* d_ws, size_t ws_size,
                              hipStream_t stream) {
  const float* x = (const float*)d_in[0];
  const float* mask = (const float*)d_in[1];
  const float* Wq = (const float*)d_in[2];
  const float* bq = (const float*)d_in[3];
  const float* Wk = (const float*)d_in[4];
  const float* bk = (const float*)d_in[5];
  const float* Wv = (const float*)d_in[6];
  const float* bv = (const float*)d_in[7];
  float* out = (float*)d_out;

  char* ws = (char*)d_ws;
  const size_t NEED = 28308992;
  if (ws_size < NEED) return;  // fail cleanly rather than OOB
  unsigned short* xbf  = (unsigned short*)ws;              // 2,064,384 B
  unsigned short* wbf  = (unsigned short*)(ws + 2064384);  //   983,040 B
  unsigned short* qbf  = (unsigned short*)(ws + 3047424);  // 5,242,880 B
  unsigned short* kbf  = (unsigned short*)(ws + 8290304);  // 5,242,880 B
  unsigned short* vrow = (unsigned short*)(ws + 13533184); // 5,242,880 B
  unsigned short* vT   = (unsigned short*)(ws + 18776064); // 5,242,880 B
  float*          mpad = (float*)(ws + 24018944);          // 4,128,768 B
  float*          rsbuf = (float*)(ws + 28147712);         //   161,280 B

  convert_kernel<<<9984, 256, 0, stream>>>(x, Wq, Wk, Wv, mask, xbf, wbf, mpad);
  proj_kernel<<<1512, 256, 0, stream>>>(xbf, wbf, bq, bk, bv, qbf, kbf, vrow);
  transpose_v<<<640, 256, 0, stream>>>(vrow, vT);
  attn_kernel<<<2520, 256, 0, stream>>>(qbf, kbf, vT, mpad, rsbuf, out);
  wsum_kernel<<<1008, 256, 0, stream>>>(qbf, kbf, rsbuf, mask, out);
}

// Round 2
// 257.543 us; speedup vs baseline: 1.0298x; 1.0298x over previous
//
#include <hip/hip_runtime.h>
#include <stdint.h>

#define B_ 4
#define S_ 1001
#define SP 1008    // padded rows (63 * 16)
#define SPAD 1024  // padded t dimension (32 * 32)
#define EIN_ 256
#define EOUT_ 64
#define H_ 10
#define NCOL 640   // H*EOUT
#define NCOL3 1920
#define SCW 1016   // sc row stride in bf16 (1008 cols + 8 pad); 16*SCW*2+16+64 = 32592 B -> 5 blocks/CU by LDS

typedef short bf16x8 __attribute__((ext_vector_type(8)));
typedef short bf16x4 __attribute__((ext_vector_type(4)));
typedef float f32x4 __attribute__((ext_vector_type(4)));

__device__ __forceinline__ unsigned short f2bf(float f) {
  unsigned u = __float_as_uint(f);
  u += 0x7FFFu + ((u >> 16) & 1u);  // RTNE (inputs finite)
  return (unsigned short)(u >> 16);
}
__device__ __forceinline__ float bf2f(unsigned short h) {
  return __uint_as_float(((unsigned)h) << 16);
}

// ---- kernel 1: fp32 -> bf16 (x padded, W concat) + mask zero-padded fp32 ----
__global__ __launch_bounds__(256) void convert_kernel(
    const float* __restrict__ x, const float* __restrict__ Wq,
    const float* __restrict__ Wk, const float* __restrict__ Wv,
    const float* __restrict__ mask, unsigned short* __restrict__ xbf,
    unsigned short* __restrict__ wbf, float* __restrict__ mpad) {
  int i = blockIdx.x * 256 + threadIdx.x;
  const int N1 = B_ * SP * EIN_;   // 1,032,192
  const int N2 = NCOL3 * EIN_;     // 491,520
  const int N3 = SP * SPAD;        // 1,032,192
  if (i < N1) {
    int b = i / (SP * EIN_);
    int rem = i % (SP * EIN_);
    int row = rem / EIN_;
    int e = rem % EIN_;
    float v = (row < S_) ? x[((size_t)(b * S_ + row)) * EIN_ + e] : 0.0f;
    xbf[i] = f2bf(v);
  } else if (i < N1 + N2) {
    int j = i - N1;
    int col = j / EIN_;
    int e = j % EIN_;
    int mat = col / NCOL;
    int hcol = col % NCOL;
    const float* W = (mat == 0) ? Wq : (mat == 1) ? Wk : Wv;
    wbf[j] = f2bf(W[(size_t)hcol * EIN_ + e]);
  } else if (i < N1 + N2 + N3) {
    int j = i - N1 - N2;
    int row = j >> 10;
    int col = j & 1023;
    mpad[j] = (row < S_ && col < S_) ? mask[(size_t)row * S_ + col] : 0.0f;
  }
}

// ---------------- kernel 2: projection GEMM (MFMA bf16), 6-way N split ------
__global__ __launch_bounds__(256) void proj_kernel(
    const unsigned short* __restrict__ xbf, const unsigned short* __restrict__ wbf,
    const float* __restrict__ bq, const float* __restrict__ bk,
    const float* __restrict__ bv, unsigned short* __restrict__ qbf,
    unsigned short* __restrict__ kbf, unsigned short* __restrict__ vrow) {
  int tid = threadIdx.x;
  int wv_ = tid >> 6;
  int l = tid & 63;
  int qd = l >> 4;
  int c = l & 15;
  int bid = blockIdx.x;
  int g = bid % 6;
  int t2 = bid / 6;
  int b = t2 / 63;
  int tile = t2 % 63;
  int s0 = tile * 16;

  bf16x8 af[8];
  const unsigned short* xrowp = xbf + (size_t)(b * SP + s0 + c) * EIN_;
#pragma unroll
  for (int ks = 0; ks < 8; ++ks)
    af[ks] = *(const bf16x8*)(xrowp + ks * 32 + qd * 8);

  for (int nt = g * 20 + wv_; nt < g * 20 + 20; nt += 4) {
    int col0 = nt * 16;
    f32x4 acc = {0.f, 0.f, 0.f, 0.f};
    const unsigned short* wrow = wbf + (size_t)(col0 + c) * EIN_;
#pragma unroll
    for (int ks = 0; ks < 8; ++ks) {
      bf16x8 bfg = *(const bf16x8*)(wrow + ks * 32 + qd * 8);
      acc = __builtin_amdgcn_mfma_f32_16x16x32_bf16(af[ks], bfg, acc, 0, 0, 0);
    }
    int col = col0 + c;
    int mat = col / NCOL;
    int hcol = col % NCOL;
    int hh = hcol >> 6;
    int o = hcol & 63;
    const float* bias = (mat == 0) ? bq : (mat == 1) ? bk : bv;
    float bb = bias[hcol];
    unsigned short* dst = (mat == 0) ? qbf : (mat == 1) ? kbf : vrow;
    size_t base = ((size_t)(b * H_ + hh)) * SPAD * EOUT_ + o;
#pragma unroll
    for (int i = 0; i < 4; ++i) {
      int srow = s0 + qd * 4 + i;
      float v = (srow < S_) ? (acc[i] + bb) : 0.0f;  // zero pad rows
      dst[base + (size_t)srow * EOUT_] = f2bf(v);
    }
  }
}

// ---------------- kernel 3: v [t][o] -> vT [o][t] ----------------
// Explicitly zeroes vT for t >= 1008 (proj never writes those rows), so the
// attention kernel's k-tail MFMAs see guaranteed-zero B fragments.
__global__ __launch_bounds__(256) void transpose_v(
    const unsigned short* __restrict__ vrow, unsigned short* __restrict__ vT) {
  __shared__ unsigned short tl[64 * 65];
  int bid = blockIdx.x;
  int bh = bid >> 4;
  int t0 = (bid & 15) * 64;
  int tid = threadIdx.x;
#pragma unroll
  for (int i = 0; i < 16; ++i) {
    int idx = i * 256 + tid;
    int o = idx & 63;
    int t_l = idx >> 6;
    int row = t0 + t_l;
    tl[o * 65 + t_l] =
        (row < SP) ? vrow[((size_t)bh * SPAD + row) * EOUT_ + o] : (unsigned short)0;
  }
  __syncthreads();
#pragma unroll
  for (int i = 0; i < 16; ++i) {
    int idx = i * 256 + tid;
    int t_l = idx & 63;
    int o = idx >> 6;
    vT[((size_t)bh * EOUT_ + o) * SPAD + t0 + t_l] = tl[o * 65 + t_l];
  }
}

// ---------------- kernel 4: attention (concat out + rs export) ----------------
// Latency-chain fix: batch-4 load groups in phases A and D (8 / 8 outstanding
// loads per group), hoisted loads in phase B. launch_bounds(256,4) -> 128 VGPR
// budget so the batched fragments stay in registers.
// 2-D XCD partition: grid 2560 = 8 XCD * 320. XCD x owns (tile-half xr) x
// (bh-quarter xc); processed in two 5-bh sub-phases. Per-XCD working set:
// 2 MB mask slice + 5*(K+V 256 KB) ~= 3.25 MB < 4 MB L2.
__global__ __launch_bounds__(256, 4) void attn_kernel(
    const unsigned short* __restrict__ qbf, const unsigned short* __restrict__ kbf,
    const unsigned short* __restrict__ vT, const float* __restrict__ mpad,
    float* __restrict__ rsbuf, float* __restrict__ out) {
  __shared__ unsigned short sc[16 * SCW + 8];  // +8 bf16 = 16 B zero guard
  __shared__ float rs[16];

  int tid = threadIdx.x;
  int wv_ = tid >> 6;
  int l = tid & 63;
  int qd = l >> 4;
  int c = l & 15;

  int bid0 = blockIdx.x;
  int x_ = bid0 & 7;        // XCD (hw round-robins consecutive bids)
  int s_ = bid0 >> 3;       // 0..319 slot within XCD
  int xr = x_ >> 2;         // tile half (0..1)
  int xc = x_ & 3;          // bh quarter (0..3)
  int sub = s_ / 160;       // 5-bh sub-phase (0..1)
  int m_ = s_ % 160;
  int ti = m_ / 5;          // 0..31
  int bhi = m_ % 5;
  int tile = xr * 32 + ti;  // 0..63
  if (tile >= 63) return;   // 40 pad blocks
  int bh_ = xc * 10 + sub * 5 + bhi;  // 0..39
  int b = bh_ / 10;
  int h = bh_ % 10;
  int s0 = tile * 16;

  if (tid < 16) rs[tid] = 0.0f;

  float* concat = out;  // [B,S,640]

  size_t bh = (size_t)(b * H_ + h);
  const unsigned short* qb = qbf + bh * SPAD * EOUT_;
  const unsigned short* kb = kbf + bh * SPAD * EOUT_;
  const unsigned short* vb = vT + bh * EOUT_ * SPAD;

  // ---- phase A: scores = (Q K^T)/16, bf16 into LDS; batch-4 t-tiles ----
  bf16x8 aq0 = *(const bf16x8*)(qb + (size_t)(s0 + c) * EOUT_ + qd * 8);
  bf16x8 aq1 = *(const bf16x8*)(qb + (size_t)(s0 + c) * EOUT_ + 32 + qd * 8);
#pragma unroll
  for (int g = 0; g < 4; ++g) {
    bf16x8 k0[4], k1[4];
#pragma unroll
    for (int j = 0; j < 4; ++j) {
      int t0 = (wv_ + 4 * (g * 4 + j)) * 16;
      const unsigned short* krow = kb + (size_t)(t0 + c) * EOUT_ + qd * 8;
      k0[j] = *(const bf16x8*)krow;
      k1[j] = *(const bf16x8*)(krow + 32);
    }
#pragma unroll
    for (int j = 0; j < 4; ++j) {
      f32x4 acc = {0.f, 0.f, 0.f, 0.f};
      acc = __builtin_amdgcn_mfma_f32_16x16x32_bf16(aq0, k0[j], acc, 0, 0, 0);
      acc = __builtin_amdgcn_mfma_f32_16x16x32_bf16(aq1, k1[j], acc, 0, 0, 0);
      int t0 = (wv_ + 4 * (g * 4 + j)) * 16;
#pragma unroll
      for (int i = 0; i < 4; ++i)
        sc[(qd * 4 + i) * SCW + t0 + c] = f2bf(acc[i] * 0.0625f);
    }
  }
  // cols 1008..1015 of each row + the 16 B guard after row 15 must be finite
  // (phase D k-tail reads them against zero B fragments): zero them.
  if (tid < 128) sc[(tid >> 3) * SCW + 1008 + (tid & 7)] = 0;
  if (tid < 8) sc[16 * SCW + tid] = 0;
  __syncthreads();

  // ---- phase B: row-per-wave; l = exp(s)*mask, rs per row; hoisted loads ----
#pragma unroll
  for (int rr = 0; rr < 4; ++rr) {
    int r = wv_ * 4 + rr;
    int srow = s0 + r;
    if (srow < S_) {
      const float* mrow = mpad + (size_t)srow * SPAD;
      bf16x4 sv[4];
      f32x4 mv[4];
      bool tail = (l < 60);
#pragma unroll
      for (int ci = 0; ci < 3; ++ci) {
        int t0c = ci * 256 + 4 * l;
        sv[ci] = *(const bf16x4*)&sc[r * SCW + t0c];
        mv[ci] = *(const f32x4*)(mrow + t0c);
      }
      if (tail) {
        int t0c = 768 + 4 * l;
        sv[3] = *(const bf16x4*)&sc[r * SCW + t0c];
        mv[3] = *(const f32x4*)(mrow + t0c);
      }
      float nacc = 0.0f;
#pragma unroll
      for (int ci = 0; ci < 3; ++ci) {
        int t0c = ci * 256 + 4 * l;
        bf16x4 lvv;
#pragma unroll
        for (int j = 0; j < 4; ++j) {
          float e = __expf(bf2f((unsigned short)sv[ci][j]));
          float lval = e * mv[ci][j];  // mpad pad cols are 0 -> lval 0
          nacc += lval * lval;
          lvv[j] = (short)f2bf(lval);
        }
        *(bf16x4*)&sc[r * SCW + t0c] = lvv;
      }
      if (tail) {  // tail chunk: cols 768..1007
        int t0c = 768 + 4 * l;
        bf16x4 lvv;
#pragma unroll
        for (int j = 0; j < 4; ++j) {
          float e = __expf(bf2f((unsigned short)sv[3][j]));
          float lval = e * mv[3][j];
          nacc += lval * lval;
          lvv[j] = (short)f2bf(lval);
        }
        *(bf16x4*)&sc[r * SCW + t0c] = lvv;
      }
      nacc += __shfl_xor(nacc, 1);
      nacc += __shfl_xor(nacc, 2);
      nacc += __shfl_xor(nacc, 4);
      nacc += __shfl_xor(nacc, 8);
      nacc += __shfl_xor(nacc, 16);
      nacc += __shfl_xor(nacc, 32);
      if (l == 0) rs[r] = 1.0f / fmaxf(sqrtf(nacc), 1e-12f);
    }
  }
  __syncthreads();

  if (tid < 16) rsbuf[((size_t)bh * 63 + tile) * 16 + tid] = rs[tid];

  // ---- phase D: out = (l V) * rs[row]; batch-4 ksteps ----
  // kstep 31 reads A cols 992..1023: 992..1007 real, 1008..1015 zeroed,
  // 1016..1023 wrap to next row / guard (finite) -- all multiplied by
  // vT[t>=1008] == 0, so contribution is exactly 0.
  f32x4 oacc = {0.f, 0.f, 0.f, 0.f};
  const unsigned short* vrow_ = vb + (size_t)(wv_ * 16 + c) * SPAD;
#pragma unroll
  for (int g = 0; g < 8; ++g) {
    bf16x8 afr[4], bfr[4];
#pragma unroll
    for (int j = 0; j < 4; ++j) {
      int kstep = g * 4 + j;
      afr[j] = *(const bf16x8*)&sc[c * SCW + kstep * 32 + qd * 8];
      bfr[j] = *(const bf16x8*)(vrow_ + kstep * 32 + qd * 8);
    }
#pragma unroll
    for (int j = 0; j < 4; ++j)
      oacc = __builtin_amdgcn_mfma_f32_16x16x32_bf16(afr[j], bfr[j], oacc, 0, 0, 0);
  }
#pragma unroll
  for (int i = 0; i < 4; ++i) {
    int row = qd * 4 + i;
    int srow = s0 + row;
    if (srow < S_)
      concat[((size_t)(b * S_) + srow) * NCOL + h * EOUT_ + wv_ * 16 + c] =
          oacc[i] * rs[row];
  }
}

// ---- kernel 5: wsum[b,s,t] = mask[s,t] * sum_h rs_h[s] * exp(score_h[s,t]) ----
// Recomputes QK^T per head (MFMA-cheap); exp + head-sum stay in C-layout regs.
__global__ __launch_bounds__(256) void wsum_kernel(
    const unsigned short* __restrict__ qbf, const unsigned short* __restrict__ kbf,
    const float* __restrict__ rsbuf, const float* __restrict__ mask,
    float* __restrict__ out) {
  __shared__ float wrs[H_ * 16];
  int tid = threadIdx.x;
  int wv_ = tid >> 6;
  int l = tid & 63;
  int qd = l >> 4;
  int c = l & 15;
  int bid0 = blockIdx.x;
  // XCD swizzle: 1008 = 8 * 126; co-locate same-tile blocks per XCD.
  int bid = (bid0 & 7) * 126 + (bid0 >> 3);
  int tchunk = bid & 3;
  int rem = bid >> 2;
  int tile = rem % 63;
  int b = rem / 63;
  int s0 = tile * 16;
  int tb = tchunk * 256 + wv_ * 64;

  if (tid < H_ * 16) {
    int h = tid >> 4, row = tid & 15;
    wrs[tid] = rsbuf[((size_t)(b * H_ + h) * 63 + tile) * 16 + row];
  }
  __syncthreads();

  float wacc[16];
#pragma unroll
  for (int i = 0; i < 16; ++i) wacc[i] = 0.0f;

  for (int h = 0; h < H_; ++h) {
    size_t bh = (size_t)(b * H_ + h);
    const unsigned short* qb = qbf + bh * SPAD * EOUT_;
    const unsigned short* kb = kbf + bh * SPAD * EOUT_;
    bf16x8 aq0 = *(const bf16x8*)(qb + (size_t)(s0 + c) * EOUT_ + qd * 8);
    bf16x8 aq1 = *(const bf16x8*)(qb + (size_t)(s0 + c) * EOUT_ + 32 + qd * 8);
    f32x4 acc[4];
#pragma unroll
    for (int st = 0; st < 4; ++st) {
      const unsigned short* krow =
          kb + (size_t)(tb + st * 16 + c) * EOUT_ + qd * 8;
      f32x4 a = {0.f, 0.f, 0.f, 0.f};
      a = __builtin_amdgcn_mfma_f32_16x16x32_bf16(aq0, *(const bf16x8*)krow, a, 0, 0, 0);
      a = __builtin_amdgcn_mfma_f32_16x16x32_bf16(aq1, *(const bf16x8*)(krow + 32), a, 0, 0, 0);
      acc[st] = a;
    }
#pragma unroll
    for (int st = 0; st < 4; ++st)
#pragma unroll
      for (int i = 0; i < 4; ++i)
        wacc[st * 4 + i] += wrs[h * 16 + qd * 4 + i] * __expf(acc[st][i] * 0.0625f);
  }

  float* wsum = out + (size_t)B_ * S_ * NCOL;
#pragma unroll
  for (int st = 0; st < 4; ++st) {
    int t = tb + st * 16 + c;
#pragma unroll
    for (int i = 0; i < 4; ++i) {
      int srow = s0 + qd * 4 + i;
      if (srow < S_ && t < S_)
        wsum[((size_t)b * S_ + srow) * S_ + t] =
            wacc[st * 4 + i] * mask[(size_t)srow * S_ + t];
    }
  }
}

extern "C" void kernel_launch(void* const* d_in, const int* in_sizes, int n_in,
                              void* d_out, int out_size, void* d_ws, size_t ws_size,
                              hipStream_t stream) {
  const float* x = (const float*)d_in[0];
  const float* mask = (const float*)d_in[1];
  const float* Wq = (const float*)d_in[2];
  const float* bq = (const float*)d_in[3];
  const float* Wk = (const float*)d_in[4];
  const float* bk = (const float*)d_in[5];
  const float* Wv = (const float*)d_in[6];
  const float* bv = (const float*)d_in[7];
  float* out = (float*)d_out;

  char* ws = (char*)d_ws;
  const size_t NEED = 28308992;
  if (ws_size < NEED) return;  // fail cleanly rather than OOB
  unsigned short* xbf  = (unsigned short*)ws;              // 2,064,384 B
  unsigned short* wbf  = (unsigned short*)(ws + 2064384);  //   983,040 B
  unsigned short* qbf  = (unsigned short*)(ws + 3047424);  // 5,242,880 B
  unsigned short* kbf  = (unsigned short*)(ws + 8290304);  // 5,242,880 B
  unsigned short* vrow = (unsigned short*)(ws + 13533184); // 5,242,880 B
  unsigned short* vT   = (unsigned short*)(ws + 18776064); // 5,242,880 B
  float*          mpad = (float*)(ws + 24018944);          // 4,128,768 B
  float*          rsbuf = (float*)(ws + 28147712);         //   161,280 B

  convert_kernel<<<9984, 256, 0, stream>>>(x, Wq, Wk, Wv, mask, xbf, wbf, mpad);
  proj_kernel<<<1512, 256, 0, stream>>>(xbf, wbf, bq, bk, bv, qbf, kbf, vrow);
  transpose_v<<<640, 256, 0, stream>>>(vrow, vT);
  attn_kernel<<<2560, 256, 0, stream>>>(qbf, kbf, vT, mpad, rsbuf, out);
  wsum_kernel<<<1008, 256, 0, stream>>>(qbf, kbf, rsbuf, mask, out);
}